// Round 2
// baseline (646.211 us; speedup 1.0000x reference)
//
#include <hip/hip_runtime.h>
#include <hip/hip_bf16.h>
#include <stdint.h>

#define NF 8192
#define NX 2048
#define MROWS 8192
#define NGROUPS 32

typedef unsigned short u16;
typedef __bf16 bf16x8 __attribute__((ext_vector_type(8)));
typedef float f32x16 __attribute__((ext_vector_type(16)));

#define AS1 __attribute__((address_space(1)))
#define AS3 __attribute__((address_space(3)))

// async global->LDS, 16B per lane. LDS dest = wave-uniform base + lane*16,
// which matches per-lane &lds[t*8] when t = wave*64 + lane (guide §5, m97/m104).
__device__ __forceinline__ void glds16(const void* g, void* l) {
    __builtin_amdgcn_global_load_lds((AS1 void*)(uintptr_t)g,
                                     (AS3 void*)(uintptr_t)l, 16, 0, 0);
}

__device__ __forceinline__ u16 f2bf(float f) {
    unsigned u = __float_as_uint(f);
    return (u16)((u + 0x7FFFu + ((u >> 16) & 1u)) >> 16);  // RNE
}

// Fused prep, one dispatch:
//  blocks [0, 16384):      x fp32 [M,K] -> bf16 (float4 per thread)
//  blocks [16384, 49152):  packed int4 -> W bf16 [NF, NX] row-major
__global__ void prep_kernel(const float4* __restrict__ x, ushort4* __restrict__ Xb,
                            const int* __restrict__ packed,
                            const float* __restrict__ scales,
                            const int* __restrict__ zeros,
                            uint32_t* __restrict__ W2) {
    int b = blockIdx.x;
    if (b < 16384) {
        int i = b * 256 + threadIdx.x;          // [0, M*K/4)
        float4 v = x[i];
        ushort4 o;
        o.x = f2bf(v.x); o.y = f2bf(v.y); o.z = f2bf(v.z); o.w = f2bf(v.w);
        Xb[i] = o;
    } else {
        int tid = (b - 16384) * 256 + threadIdx.x;  // [0, NF*NX/2)
        int f = tid >> 10;                           // NX/2 = 1024 per row
        int i = tid & 1023;
        int g = f * NGROUPS + (i >> 5);
        int p = packed[tid];
        float s = scales[g];
        float z = (float)zeros[g];
        float w0 = ((float)(p & 15) - z) * s;
        float w1 = ((float)((p >> 4) & 15) - z) * s;
        W2[tid] = (uint32_t)f2bf(w0) | ((uint32_t)f2bf(w1) << 16);
    }
}

// C[M,N] = A[M,K] * B[N,K]^T + bias
// 128x128 tile, BK=32, 4 waves (2x2 of 64x64 per wave, 2x2 of 32x32 MFMA tiles),
// mfma_f32_32x32x16_bf16, global_load_lds width-16 staging (m97 structure).
__global__ __launch_bounds__(256)
void gemm_kernel(const u16* __restrict__ A, const u16* __restrict__ B,
                 const float* __restrict__ bias, float* __restrict__ C) {
    __shared__ __align__(16) u16 As[128 * 32];
    __shared__ __align__(16) u16 Bs[128 * 32];

    const int t = threadIdx.x;
    const int rowA0 = blockIdx.y * 128;
    const int rowB0 = blockIdx.x * 128;

    // staging: 512 chunks of 16B per tile; chunk c -> row c>>2, k-offset (c&3)*8.
    const u16* pa0 = A + (size_t)(rowA0 + (t >> 2)) * NX + (t & 3) * 8;
    const u16* pa1 = pa0 + (size_t)64 * NX;
    const u16* pb0 = B + (size_t)(rowB0 + (t >> 2)) * NX + (t & 3) * 8;
    const u16* pb1 = pb0 + (size_t)64 * NX;
    u16* sa0 = &As[t * 8];
    u16* sa1 = &As[(t + 256) * 8];
    u16* sb0 = &Bs[t * 8];
    u16* sb1 = &Bs[(t + 256) * 8];

    const int lane = t & 63;
    const int wv = t >> 6;
    const int wm = (wv & 1) * 64;   // wave row offset in tile
    const int wn = (wv >> 1) * 64;  // wave col offset in tile
    const int l31 = lane & 31;
    const int h = lane >> 5;        // k-half selector for A/B frags

    // A/B operand layout (32x32x16): lane holds row = lane&31,
    // k = (lane>>5)*8 + [0..8)  -> contiguous 16B in row-major LDS.
    const u16* Af = &As[(wm + l31) * 32 + h * 8];
    const u16* Bf = &Bs[(wn + l31) * 32 + h * 8];

    f32x16 acc[2][2];
#pragma unroll
    for (int i = 0; i < 2; ++i)
#pragma unroll
        for (int j = 0; j < 2; ++j) acc[i][j] = (f32x16)(0.f);

    for (int kk = 0; kk < NX / 32; ++kk) {
        glds16(pa0, sa0);
        glds16(pa1, sa1);
        glds16(pb0, sb0);
        glds16(pb1, sb1);
        pa0 += 32; pa1 += 32; pb0 += 32; pb1 += 32;
        __syncthreads();  // drains vmcnt then barrier: LDS tiles ready

#pragma unroll
        for (int kt = 0; kt < 2; ++kt) {  // two K-16 steps inside the K-32 tile
            bf16x8 a[2], b[2];
#pragma unroll
            for (int i = 0; i < 2; ++i) a[i] = *(const bf16x8*)(Af + i * 32 * 32 + kt * 16);
#pragma unroll
            for (int j = 0; j < 2; ++j) b[j] = *(const bf16x8*)(Bf + j * 32 * 32 + kt * 16);
#pragma unroll
            for (int i = 0; i < 2; ++i)
#pragma unroll
                for (int j = 0; j < 2; ++j)
                    acc[i][j] = __builtin_amdgcn_mfma_f32_32x32x16_bf16(a[i], b[j], acc[i][j], 0, 0, 0);
        }

        __syncthreads();  // all waves done reading before next overwrite
    }

    // epilogue: C/D layout col = lane&31, row = (reg&3) + 8*(reg>>2) + 4*(lane>>5)
    // (m74/m101 verified). Each store instr = 2 rows x 32 contiguous cols
    // = 2 full 128B lines -> no partial-line RFO. Nontemporal to spare LLC.
#pragma unroll
    for (int j = 0; j < 2; ++j) {
        const int col = rowB0 + wn + j * 32 + l31;
        const float bv = bias[col];
#pragma unroll
        for (int i = 0; i < 2; ++i) {
            const int row_base = rowA0 + wm + i * 32 + 4 * h;
#pragma unroll
            for (int r = 0; r < 16; ++r) {
                const int row = row_base + (r & 3) + 8 * (r >> 2);
                __builtin_nontemporal_store(acc[i][j][r] + bv, C + (size_t)row * NF + col);
            }
        }
    }
}

extern "C" void kernel_launch(void* const* d_in, const int* in_sizes, int n_in,
                              void* d_out, int out_size, void* d_ws, size_t ws_size,
                              hipStream_t stream) {
    const float* x      = (const float*)d_in[0];   // [4,2048,2048] fp32
    const int* packed   = (const int*)d_in[1];     // [8192,1024]
    const float* scales = (const float*)d_in[2];   // [8192,32]
    const int* zeros    = (const int*)d_in[3];     // [8192,32]
    const float* bias   = (const float*)d_in[4];   // [8192]
    float* out = (float*)d_out;                    // [8192, 8192] fp32

    // workspace: W bf16 (32 MiB) + x bf16 (32 MiB); fully rewritten every call
    u16* Wq = (u16*)d_ws;
    u16* Xb = Wq + (size_t)NF * NX;

    prep_kernel<<<49152, 256, 0, stream>>>((const float4*)x, (ushort4*)Xb,
                                           packed, scales, zeros, (uint32_t*)Wq);

    dim3 grid(NF / 128, MROWS / 128);
    gemm_kernel<<<grid, 256, 0, stream>>>(Xb, Wq, bias, out);
}